// Round 5
// baseline (447.888 us; speedup 1.0000x reference)
//
#include <hip/hip_runtime.h>
#include <hip/hip_bf16.h>

// ===== ROUND 5: ATTRIBUTION PROBE =====
// Real pipeline is round-1's best (fused k_agg, no sort). Added: 2 duplicate
// k_agg launches + 1 duplicate k_h_p launch writing to scratch workspace.
// Outputs are bit-identical to round-1; the duplicates only exist so that
// dur_us - 365 = 2*T(k_agg) + T(k_h_p) + 3*launch_overhead, resolving the
// ~130us attribution gap that four optimization rounds failed to localize.

#define NN 8192
#define INC 128
#define HC 256          // HEADS*OUT
#define NPB 16          // nodes per block in k_h_p
#define NGRP (NN / NPB) // 512 blocks
#define APB 4           // nodes per block in k_agg (one wave per node)
#define AGRID (NN / APB)
#define SCALE_BLOCKS 512
#define MAXDEG 32       // rows built from 32 draws -> <=32 distinct edges/node

// K1: h = x@W+b ; ps/pd = h@att1 halves. 16 nodes/block. (round-1, unchanged)
__global__ __launch_bounds__(256) void k_h_p(
    const float* __restrict__ x, const float* __restrict__ W,
    const float* __restrict__ bias, const float* __restrict__ att1,
    const int* __restrict__ ei, float* __restrict__ h,
    float* __restrict__ ps, float* __restrict__ pd,
    int* __restrict__ offs, int E) {
  int t = threadIdx.x;
  int n0 = blockIdx.x * NPB;
  // CSR build (overlaps with staging)
  for (int e = blockIdx.x * 256 + t; e < E; e += NGRP * 256) {
    if (e == 0) offs[0] = 0;
    else { int s1 = ei[e]; if (s1 != ei[e - 1]) offs[s1] = e; }
    if (e == E - 1) offs[NN] = E;
  }
  __shared__ float xs[NPB * INC];   // 8 KB, natural [n][d]
  __shared__ float hs[NPB * HC];    // 16 KB, natural [n][c]
  {
    const float4* xin = (const float4*)(x + (size_t)n0 * INC);
    ((float4*)xs)[t] = xin[t];
    ((float4*)xs)[t + 256] = xin[t + 256];
  }
  __syncthreads();
  int cg = t & 63, ng = t >> 6;     // ng == wave id (wave-uniform)
  // ---- h phase: nodes ng*4..+3, cols cg*4..+3 ----
  {
    float4 b4 = *(const float4*)&bias[cg * 4];
    float4 a0 = b4, a1 = b4, a2 = b4, a3 = b4;
    const float* xr0 = xs + (ng * 4 + 0) * INC;
    const float* xr1 = xs + (ng * 4 + 1) * INC;
    const float* xr2 = xs + (ng * 4 + 2) * INC;
    const float* xr3 = xs + (ng * 4 + 3) * INC;
    #pragma unroll 2
    for (int d = 0; d < INC; d += 4) {
      float4 xv0 = *(const float4*)&xr0[d];      // b128 broadcast reads
      float4 xv1 = *(const float4*)&xr1[d];
      float4 xv2 = *(const float4*)&xr2[d];
      float4 xv3 = *(const float4*)&xr3[d];
      const float* f0 = (const float*)&xv0;
      const float* f1 = (const float*)&xv1;
      const float* f2 = (const float*)&xv2;
      const float* f3 = (const float*)&xv3;
      #pragma unroll
      for (int k = 0; k < 4; ++k) {              // k compile-time
        float4 w4 = *(const float4*)&W[(size_t)(d + k) * HC + cg * 4];
        float x0 = f0[k], x1 = f1[k], x2 = f2[k], x3 = f3[k];
        a0.x += x0 * w4.x; a0.y += x0 * w4.y; a0.z += x0 * w4.z; a0.w += x0 * w4.w;
        a1.x += x1 * w4.x; a1.y += x1 * w4.y; a1.z += x1 * w4.z; a1.w += x1 * w4.w;
        a2.x += x2 * w4.x; a2.y += x2 * w4.y; a2.z += x2 * w4.z; a2.w += x2 * w4.w;
        a3.x += x3 * w4.x; a3.y += x3 * w4.y; a3.z += x3 * w4.z; a3.w += x3 * w4.w;
      }
    }
    float4* hb = (float4*)&hs[(ng * 4) * HC + cg * 4];
    *(float4*)&h[(size_t)(n0 + ng * 4 + 0) * HC + cg * 4] = a0;
    *(float4*)&h[(size_t)(n0 + ng * 4 + 1) * HC + cg * 4] = a1;
    *(float4*)&h[(size_t)(n0 + ng * 4 + 2) * HC + cg * 4] = a2;
    *(float4*)&h[(size_t)(n0 + ng * 4 + 3) * HC + cg * 4] = a3;
    hb[0] = a0; hb[HC / 4] = a1; hb[2 * HC / 4] = a2; hb[3 * HC / 4] = a3;
  }
  __syncthreads();
  // ---- p phase: sel = cg>>4 -> (head, isdst); f = (cg&15)*4 ----
  {
    int fg = cg & 15, sel = cg >> 4;
    int head = sel & 1, isdst = sel >> 1;
    const float* a1p = att1 + isdst * 128 * 64 + fg * 4;
    float4 p0 = {0,0,0,0}, p1 = {0,0,0,0}, p2 = {0,0,0,0}, p3 = {0,0,0,0};
    const float* hr0 = hs + (ng * 4 + 0) * HC + head * 128;
    const float* hr1 = hs + (ng * 4 + 1) * HC + head * 128;
    const float* hr2 = hs + (ng * 4 + 2) * HC + head * 128;
    const float* hr3 = hs + (ng * 4 + 3) * HC + head * 128;
    #pragma unroll 2
    for (int d = 0; d < 128; d += 4) {
      float4 hv0 = *(const float4*)&hr0[d];
      float4 hv1 = *(const float4*)&hr1[d];
      float4 hv2 = *(const float4*)&hr2[d];
      float4 hv3 = *(const float4*)&hr3[d];
      const float* g0 = (const float*)&hv0;
      const float* g1 = (const float*)&hv1;
      const float* g2 = (const float*)&hv2;
      const float* g3 = (const float*)&hv3;
      #pragma unroll
      for (int k = 0; k < 4; ++k) {
        float4 a4 = *(const float4*)&a1p[(size_t)(d + k) * 64];
        float h0 = g0[k], h1 = g1[k], h2 = g2[k], h3 = g3[k];
        p0.x += h0 * a4.x; p0.y += h0 * a4.y; p0.z += h0 * a4.z; p0.w += h0 * a4.w;
        p1.x += h1 * a4.x; p1.y += h1 * a4.y; p1.z += h1 * a4.z; p1.w += h1 * a4.w;
        p2.x += h2 * a4.x; p2.y += h2 * a4.y; p2.z += h2 * a4.z; p2.w += h2 * a4.w;
        p3.x += h3 * a4.x; p3.y += h3 * a4.y; p3.z += h3 * a4.z; p3.w += h3 * a4.w;
      }
    }
    float* dp = isdst ? pd : ps;
    *(float4*)&dp[(size_t)(n0 + ng * 4 + 0) * 128 + head * 64 + fg * 4] = p0;
    *(float4*)&dp[(size_t)(n0 + ng * 4 + 1) * 128 + head * 64 + fg * 4] = p1;
    *(float4*)&dp[(size_t)(n0 + ng * 4 + 2) * 128 + head * 64 + fg * 4] = p2;
    *(float4*)&dp[(size_t)(n0 + ng * 4 + 3) * 128 + head * 64 + fg * 4] = p3;
  }
}

// K2: fused score+exp+aggregate (round-1 best). One wave per node.
__global__ __launch_bounds__(256) void k_agg(
    const float* __restrict__ h, const float* __restrict__ ps,
    const float* __restrict__ pd, const int* __restrict__ ei,
    const float* __restrict__ att2, const int* __restrict__ offs,
    float* __restrict__ raw, float* __restrict__ part, int E) {
  int t = threadIdx.x, wid = t >> 6, lane = t & 63;
  int n = blockIdx.x * APB + wid;
  __shared__ float w2l[64];
  __shared__ int   dstl[APB][MAXDEG];
  if (t < 64) w2l[t] = att2[t];
  int lo = offs[n], hi = offs[n + 1];
  int m = hi - lo;                       // <= MAXDEG
  if (lane < m) dstl[wid][lane] = ei[E + lo + lane];
  __syncthreads();
  int head = lane >> 5, j = lane & 31;
  float2 psv = *(const float2*)&ps[(size_t)n * 128 + head * 64 + j * 2];
  float wa = w2l[j * 2], wb = w2l[j * 2 + 1];
  float rsum = 0.f;
  float4 a0 = {0, 0, 0, 0}, a1 = {0, 0, 0, 0};
  int i = 0;
  #pragma unroll 2
  for (; i + 2 <= m; i += 2) {
    int d0 = dstl[wid][i], d1 = dstl[wid][i + 1];
    float2 q0 = *(const float2*)&pd[(size_t)d0 * 128 + head * 64 + j * 2];
    float2 q1 = *(const float2*)&pd[(size_t)d1 * 128 + head * 64 + j * 2];
    float4 h0 = *(const float4*)&h[(size_t)d0 * HC + lane * 4];
    float4 h1 = *(const float4*)&h[(size_t)d1 * HC + lane * 4];
    float u0 = psv.x + q0.x; u0 = u0 > 0.f ? u0 : 0.01f * u0;
    float u1 = psv.y + q0.y; u1 = u1 > 0.f ? u1 : 0.01f * u1;
    float s0 = u0 * wa + u1 * wb;
    float v0 = psv.x + q1.x; v0 = v0 > 0.f ? v0 : 0.01f * v0;
    float v1 = psv.y + q1.y; v1 = v1 > 0.f ? v1 : 0.01f * v1;
    float s1 = v0 * wa + v1 * wb;
    s0 += __shfl_xor(s0, 1);  s0 += __shfl_xor(s0, 2);  s0 += __shfl_xor(s0, 4);
    s0 += __shfl_xor(s0, 8);  s0 += __shfl_xor(s0, 16);   // sum within 32-half
    s1 += __shfl_xor(s1, 1);  s1 += __shfl_xor(s1, 2);  s1 += __shfl_xor(s1, 4);
    s1 += __shfl_xor(s1, 8);  s1 += __shfl_xor(s1, 16);
    float e0 = __expf(s0), e1 = __expf(s1);
    rsum += e0; rsum += e1;              // sequential edge order
    a0.x += e0 * h0.x; a0.y += e0 * h0.y; a0.z += e0 * h0.z; a0.w += e0 * h0.w;
    a1.x += e1 * h1.x; a1.y += e1 * h1.y; a1.z += e1 * h1.z; a1.w += e1 * h1.w;
  }
  if (i < m) {                            // odd tail
    int d0 = dstl[wid][i];
    float2 q0 = *(const float2*)&pd[(size_t)d0 * 128 + head * 64 + j * 2];
    float4 h0 = *(const float4*)&h[(size_t)d0 * HC + lane * 4];
    float u0 = psv.x + q0.x; u0 = u0 > 0.f ? u0 : 0.01f * u0;
    float u1 = psv.y + q0.y; u1 = u1 > 0.f ? u1 : 0.01f * u1;
    float s0 = u0 * wa + u1 * wb;
    s0 += __shfl_xor(s0, 1);  s0 += __shfl_xor(s0, 2);  s0 += __shfl_xor(s0, 4);
    s0 += __shfl_xor(s0, 8);  s0 += __shfl_xor(s0, 16);
    float e0 = __expf(s0);
    rsum += e0;
    a0.x += e0 * h0.x; a0.y += e0 * h0.y; a0.z += e0 * h0.z; a0.w += e0 * h0.w;
  }
  if (j == 0) part[n * 2 + head] = rsum;
  float4 res;
  res.x = a0.x + a1.x; res.y = a0.y + a1.y;
  res.z = a0.z + a1.z; res.w = a0.w + a1.w;
  *(float4*)&raw[(size_t)n * HC + lane * 4] = res;
}

// K3: reduce part[8192][2] -> per-head sums (every block, L2-hot), then
//   out[n][d] = 0.5*(raw[n][d]*inv0 + raw[n][128+d]*inv1)
__global__ __launch_bounds__(256) void k_scale(
    const float* __restrict__ raw, const float* __restrict__ part,
    float* __restrict__ out) {
  int t = threadIdx.x;
  float s0 = 0.f, s1 = 0.f;
  #pragma unroll 4
  for (int k = 0; k < 32; ++k) {
    float2 p = ((const float2*)part)[t + 256 * k];
    s0 += p.x; s1 += p.y;
  }
  #pragma unroll
  for (int off = 1; off <= 32; off <<= 1) {
    s0 += __shfl_xor(s0, off);
    s1 += __shfl_xor(s1, off);
  }
  __shared__ float ws0[4], ws1[4];
  if ((t & 63) == 0) { ws0[t >> 6] = s0; ws1[t >> 6] = s1; }
  __syncthreads();
  float inv0 = 1.f / (ws0[0] + ws0[1] + ws0[2] + ws0[3]);
  float inv1 = 1.f / (ws1[0] + ws1[1] + ws1[2] + ws1[3]);
  const float4* r4 = (const float4*)raw;
  float4* o4 = (float4*)out;
  int idx = blockIdx.x * 256 + t;
  #pragma unroll
  for (int rep = 0; rep < 2; ++rep, idx += SCALE_BLOCKS * 256) {
    int nn = idx >> 5, c4 = idx & 31;
    float4 a = r4[nn * 64 + c4];               // head0 cols
    float4 b = r4[nn * 64 + 32 + c4];          // head1 cols
    float4 o;
    o.x = 0.5f * (a.x * inv0 + b.x * inv1);
    o.y = 0.5f * (a.y * inv0 + b.y * inv1);
    o.z = 0.5f * (a.z * inv0 + b.z * inv1);
    o.w = 0.5f * (a.w * inv0 + b.w * inv1);
    o4[idx] = o;
  }
}

extern "C" void kernel_launch(void* const* d_in, const int* in_sizes, int n_in,
                              void* d_out, int out_size, void* d_ws, size_t ws_size,
                              hipStream_t stream) {
  const float* x    = (const float*)d_in[0];
  // d_in[1] = theta: UNUSED by the reference (edge list precomputed)
  const float* W    = (const float*)d_in[2];
  const float* bias = (const float*)d_in[3];
  const float* att1 = (const float*)d_in[4];
  const float* att2 = (const float*)d_in[5];
  const int* ei = (const int*)d_in[6];
  int E = in_sizes[6] / 2;
  float* out = (float*)d_out;

  float* ws = (float*)d_ws;
  float* h    = ws;                         // 8 MB
  float* ps   = h  + (size_t)NN * HC;       // 4 MB
  float* pd   = ps + (size_t)NN * 128;      // 4 MB
  float* raw  = pd + (size_t)NN * 128;      // 8 MB
  float* part = raw + (size_t)NN * HC;      // 64 KB
  int*   offs = (int*)(part + (size_t)NN * 2);  // NN+1 ints

  // ---- scratch region for attribution-probe duplicates (at +48 MB) ----
  float* scr   = ws + (size_t)12 * 1024 * 1024;   // 48 MB offset (floats)
  float* h2    = scr;                              // 8 MB
  float* ps2   = h2  + (size_t)NN * HC;
  float* pd2   = ps2 + (size_t)NN * 128;
  float* raw2  = pd2 + (size_t)NN * 128;
  float* part2 = raw2 + (size_t)NN * HC;
  int*   offs2 = (int*)(part2 + (size_t)NN * 2);

  // real pipeline (identical to round-1 best)
  k_h_p<<<NGRP, 256, 0, stream>>>(x, W, bias, att1, ei, h, ps, pd, offs, E);
  k_agg<<<AGRID, 256, 0, stream>>>(h, ps, pd, ei, att2, offs, raw, part, E);
  // probe duplicates: same work, outputs to scratch (dur_us delta = cost)
  k_agg<<<AGRID, 256, 0, stream>>>(h, ps, pd, ei, att2, offs, raw2, part2, E);
  k_agg<<<AGRID, 256, 0, stream>>>(h, ps, pd, ei, att2, offs, raw2, part2, E);
  k_h_p<<<NGRP, 256, 0, stream>>>(x, W, bias, att1, ei, h2, ps2, pd2, offs2, E);
  // final output
  k_scale<<<SCALE_BLOCKS, 256, 0, stream>>>(raw, part, out);
}

// Round 6
// 363.950 us; speedup vs baseline: 1.2306x; 1.2306x over previous
//
#include <hip/hip_runtime.h>
#include <hip/hip_bf16.h>

// ===== ROUND 6: REVERT TO SESSION BEST (round-1 pipeline, probes removed) =====
// Attribution (round-5 duplicate-dispatch probe): k_agg ~30us, k_h_p ~17us,
// k_scale ~5us; remaining ~312us of dur_us is two 1-GiB harness poison fills
// (2 x ~161us). Controllable share = ~52us of ~365us; k_agg's gather runs at
// ~13 TB/s effective (random 0.5-1KB granules, 12MB set) = near L2/L3 floor.

#define NN 8192
#define INC 128
#define HC 256          // HEADS*OUT
#define NPB 16          // nodes per block in k_h_p
#define NGRP (NN / NPB) // 512 blocks
#define APB 4           // nodes per block in k_agg (one wave per node)
#define AGRID (NN / APB)
#define SCALE_BLOCKS 512
#define MAXDEG 32       // rows built from 32 draws -> <=32 distinct edges/node

// K1: h = x@W+b ; ps/pd = h@att1 halves. 16 nodes/block.
__global__ __launch_bounds__(256) void k_h_p(
    const float* __restrict__ x, const float* __restrict__ W,
    const float* __restrict__ bias, const float* __restrict__ att1,
    const int* __restrict__ ei, float* __restrict__ h,
    float* __restrict__ ps, float* __restrict__ pd,
    int* __restrict__ offs, int E) {
  int t = threadIdx.x;
  int n0 = blockIdx.x * NPB;
  // CSR build (overlaps with staging)
  for (int e = blockIdx.x * 256 + t; e < E; e += NGRP * 256) {
    if (e == 0) offs[0] = 0;
    else { int s1 = ei[e]; if (s1 != ei[e - 1]) offs[s1] = e; }
    if (e == E - 1) offs[NN] = E;
  }
  __shared__ float xs[NPB * INC];   // 8 KB, natural [n][d]
  __shared__ float hs[NPB * HC];    // 16 KB, natural [n][c]
  {
    const float4* xin = (const float4*)(x + (size_t)n0 * INC);
    ((float4*)xs)[t] = xin[t];
    ((float4*)xs)[t + 256] = xin[t + 256];
  }
  __syncthreads();
  int cg = t & 63, ng = t >> 6;     // ng == wave id (wave-uniform)
  // ---- h phase: nodes ng*4..+3, cols cg*4..+3 ----
  {
    float4 b4 = *(const float4*)&bias[cg * 4];
    float4 a0 = b4, a1 = b4, a2 = b4, a3 = b4;
    const float* xr0 = xs + (ng * 4 + 0) * INC;
    const float* xr1 = xs + (ng * 4 + 1) * INC;
    const float* xr2 = xs + (ng * 4 + 2) * INC;
    const float* xr3 = xs + (ng * 4 + 3) * INC;
    #pragma unroll 2
    for (int d = 0; d < INC; d += 4) {
      float4 xv0 = *(const float4*)&xr0[d];      // b128 broadcast reads
      float4 xv1 = *(const float4*)&xr1[d];
      float4 xv2 = *(const float4*)&xr2[d];
      float4 xv3 = *(const float4*)&xr3[d];
      const float* f0 = (const float*)&xv0;
      const float* f1 = (const float*)&xv1;
      const float* f2 = (const float*)&xv2;
      const float* f3 = (const float*)&xv3;
      #pragma unroll
      for (int k = 0; k < 4; ++k) {              // k compile-time
        float4 w4 = *(const float4*)&W[(size_t)(d + k) * HC + cg * 4];
        float x0 = f0[k], x1 = f1[k], x2 = f2[k], x3 = f3[k];
        a0.x += x0 * w4.x; a0.y += x0 * w4.y; a0.z += x0 * w4.z; a0.w += x0 * w4.w;
        a1.x += x1 * w4.x; a1.y += x1 * w4.y; a1.z += x1 * w4.z; a1.w += x1 * w4.w;
        a2.x += x2 * w4.x; a2.y += x2 * w4.y; a2.z += x2 * w4.z; a2.w += x2 * w4.w;
        a3.x += x3 * w4.x; a3.y += x3 * w4.y; a3.z += x3 * w4.z; a3.w += x3 * w4.w;
      }
    }
    float4* hb = (float4*)&hs[(ng * 4) * HC + cg * 4];
    *(float4*)&h[(size_t)(n0 + ng * 4 + 0) * HC + cg * 4] = a0;
    *(float4*)&h[(size_t)(n0 + ng * 4 + 1) * HC + cg * 4] = a1;
    *(float4*)&h[(size_t)(n0 + ng * 4 + 2) * HC + cg * 4] = a2;
    *(float4*)&h[(size_t)(n0 + ng * 4 + 3) * HC + cg * 4] = a3;
    hb[0] = a0; hb[HC / 4] = a1; hb[2 * HC / 4] = a2; hb[3 * HC / 4] = a3;
  }
  __syncthreads();
  // ---- p phase: sel = cg>>4 -> (head, isdst); f = (cg&15)*4 ----
  {
    int fg = cg & 15, sel = cg >> 4;
    int head = sel & 1, isdst = sel >> 1;
    const float* a1p = att1 + isdst * 128 * 64 + fg * 4;
    float4 p0 = {0,0,0,0}, p1 = {0,0,0,0}, p2 = {0,0,0,0}, p3 = {0,0,0,0};
    const float* hr0 = hs + (ng * 4 + 0) * HC + head * 128;
    const float* hr1 = hs + (ng * 4 + 1) * HC + head * 128;
    const float* hr2 = hs + (ng * 4 + 2) * HC + head * 128;
    const float* hr3 = hs + (ng * 4 + 3) * HC + head * 128;
    #pragma unroll 2
    for (int d = 0; d < 128; d += 4) {
      float4 hv0 = *(const float4*)&hr0[d];
      float4 hv1 = *(const float4*)&hr1[d];
      float4 hv2 = *(const float4*)&hr2[d];
      float4 hv3 = *(const float4*)&hr3[d];
      const float* g0 = (const float*)&hv0;
      const float* g1 = (const float*)&hv1;
      const float* g2 = (const float*)&hv2;
      const float* g3 = (const float*)&hv3;
      #pragma unroll
      for (int k = 0; k < 4; ++k) {
        float4 a4 = *(const float4*)&a1p[(size_t)(d + k) * 64];
        float h0 = g0[k], h1 = g1[k], h2 = g2[k], h3 = g3[k];
        p0.x += h0 * a4.x; p0.y += h0 * a4.y; p0.z += h0 * a4.z; p0.w += h0 * a4.w;
        p1.x += h1 * a4.x; p1.y += h1 * a4.y; p1.z += h1 * a4.z; p1.w += h1 * a4.w;
        p2.x += h2 * a4.x; p2.y += h2 * a4.y; p2.z += h2 * a4.z; p2.w += h2 * a4.w;
        p3.x += h3 * a4.x; p3.y += h3 * a4.y; p3.z += h3 * a4.z; p3.w += h3 * a4.w;
      }
    }
    float* dp = isdst ? pd : ps;
    *(float4*)&dp[(size_t)(n0 + ng * 4 + 0) * 128 + head * 64 + fg * 4] = p0;
    *(float4*)&dp[(size_t)(n0 + ng * 4 + 1) * 128 + head * 64 + fg * 4] = p1;
    *(float4*)&dp[(size_t)(n0 + ng * 4 + 2) * 128 + head * 64 + fg * 4] = p2;
    *(float4*)&dp[(size_t)(n0 + ng * 4 + 3) * 128 + head * 64 + fg * 4] = p3;
  }
}

// K2: fused score+exp+aggregate (session best). One wave per node.
__global__ __launch_bounds__(256) void k_agg(
    const float* __restrict__ h, const float* __restrict__ ps,
    const float* __restrict__ pd, const int* __restrict__ ei,
    const float* __restrict__ att2, const int* __restrict__ offs,
    float* __restrict__ raw, float* __restrict__ part, int E) {
  int t = threadIdx.x, wid = t >> 6, lane = t & 63;
  int n = blockIdx.x * APB + wid;
  __shared__ float w2l[64];
  __shared__ int   dstl[APB][MAXDEG];
  if (t < 64) w2l[t] = att2[t];
  int lo = offs[n], hi = offs[n + 1];
  int m = hi - lo;                       // <= MAXDEG
  if (lane < m) dstl[wid][lane] = ei[E + lo + lane];
  __syncthreads();
  int head = lane >> 5, j = lane & 31;
  float2 psv = *(const float2*)&ps[(size_t)n * 128 + head * 64 + j * 2];
  float wa = w2l[j * 2], wb = w2l[j * 2 + 1];
  float rsum = 0.f;
  float4 a0 = {0, 0, 0, 0}, a1 = {0, 0, 0, 0};
  int i = 0;
  #pragma unroll 2
  for (; i + 2 <= m; i += 2) {
    int d0 = dstl[wid][i], d1 = dstl[wid][i + 1];
    float2 q0 = *(const float2*)&pd[(size_t)d0 * 128 + head * 64 + j * 2];
    float2 q1 = *(const float2*)&pd[(size_t)d1 * 128 + head * 64 + j * 2];
    float4 h0 = *(const float4*)&h[(size_t)d0 * HC + lane * 4];
    float4 h1 = *(const float4*)&h[(size_t)d1 * HC + lane * 4];
    float u0 = psv.x + q0.x; u0 = u0 > 0.f ? u0 : 0.01f * u0;
    float u1 = psv.y + q0.y; u1 = u1 > 0.f ? u1 : 0.01f * u1;
    float s0 = u0 * wa + u1 * wb;
    float v0 = psv.x + q1.x; v0 = v0 > 0.f ? v0 : 0.01f * v0;
    float v1 = psv.y + q1.y; v1 = v1 > 0.f ? v1 : 0.01f * v1;
    float s1 = v0 * wa + v1 * wb;
    s0 += __shfl_xor(s0, 1);  s0 += __shfl_xor(s0, 2);  s0 += __shfl_xor(s0, 4);
    s0 += __shfl_xor(s0, 8);  s0 += __shfl_xor(s0, 16);   // sum within 32-half
    s1 += __shfl_xor(s1, 1);  s1 += __shfl_xor(s1, 2);  s1 += __shfl_xor(s1, 4);
    s1 += __shfl_xor(s1, 8);  s1 += __shfl_xor(s1, 16);
    float e0 = __expf(s0), e1 = __expf(s1);
    rsum += e0; rsum += e1;              // sequential edge order
    a0.x += e0 * h0.x; a0.y += e0 * h0.y; a0.z += e0 * h0.z; a0.w += e0 * h0.w;
    a1.x += e1 * h1.x; a1.y += e1 * h1.y; a1.z += e1 * h1.z; a1.w += e1 * h1.w;
  }
  if (i < m) {                            // odd tail
    int d0 = dstl[wid][i];
    float2 q0 = *(const float2*)&pd[(size_t)d0 * 128 + head * 64 + j * 2];
    float4 h0 = *(const float4*)&h[(size_t)d0 * HC + lane * 4];
    float u0 = psv.x + q0.x; u0 = u0 > 0.f ? u0 : 0.01f * u0;
    float u1 = psv.y + q0.y; u1 = u1 > 0.f ? u1 : 0.01f * u1;
    float s0 = u0 * wa + u1 * wb;
    s0 += __shfl_xor(s0, 1);  s0 += __shfl_xor(s0, 2);  s0 += __shfl_xor(s0, 4);
    s0 += __shfl_xor(s0, 8);  s0 += __shfl_xor(s0, 16);
    float e0 = __expf(s0);
    rsum += e0;
    a0.x += e0 * h0.x; a0.y += e0 * h0.y; a0.z += e0 * h0.z; a0.w += e0 * h0.w;
  }
  if (j == 0) part[n * 2 + head] = rsum;
  float4 res;
  res.x = a0.x + a1.x; res.y = a0.y + a1.y;
  res.z = a0.z + a1.z; res.w = a0.w + a1.w;
  *(float4*)&raw[(size_t)n * HC + lane * 4] = res;
}

// K3: reduce part[8192][2] -> per-head sums (every block, L2-hot), then
//   out[n][d] = 0.5*(raw[n][d]*inv0 + raw[n][128+d]*inv1)
__global__ __launch_bounds__(256) void k_scale(
    const float* __restrict__ raw, const float* __restrict__ part,
    float* __restrict__ out) {
  int t = threadIdx.x;
  float s0 = 0.f, s1 = 0.f;
  #pragma unroll 4
  for (int k = 0; k < 32; ++k) {
    float2 p = ((const float2*)part)[t + 256 * k];
    s0 += p.x; s1 += p.y;
  }
  #pragma unroll
  for (int off = 1; off <= 32; off <<= 1) {
    s0 += __shfl_xor(s0, off);
    s1 += __shfl_xor(s1, off);
  }
  __shared__ float ws0[4], ws1[4];
  if ((t & 63) == 0) { ws0[t >> 6] = s0; ws1[t >> 6] = s1; }
  __syncthreads();
  float inv0 = 1.f / (ws0[0] + ws0[1] + ws0[2] + ws0[3]);
  float inv1 = 1.f / (ws1[0] + ws1[1] + ws1[2] + ws1[3]);
  const float4* r4 = (const float4*)raw;
  float4* o4 = (float4*)out;
  int idx = blockIdx.x * 256 + t;
  #pragma unroll
  for (int rep = 0; rep < 2; ++rep, idx += SCALE_BLOCKS * 256) {
    int nn = idx >> 5, c4 = idx & 31;
    float4 a = r4[nn * 64 + c4];               // head0 cols
    float4 b = r4[nn * 64 + 32 + c4];          // head1 cols
    float4 o;
    o.x = 0.5f * (a.x * inv0 + b.x * inv1);
    o.y = 0.5f * (a.y * inv0 + b.y * inv1);
    o.z = 0.5f * (a.z * inv0 + b.z * inv1);
    o.w = 0.5f * (a.w * inv0 + b.w * inv1);
    o4[idx] = o;
  }
}

extern "C" void kernel_launch(void* const* d_in, const int* in_sizes, int n_in,
                              void* d_out, int out_size, void* d_ws, size_t ws_size,
                              hipStream_t stream) {
  const float* x    = (const float*)d_in[0];
  // d_in[1] = theta: UNUSED by the reference (edge list precomputed)
  const float* W    = (const float*)d_in[2];
  const float* bias = (const float*)d_in[3];
  const float* att1 = (const float*)d_in[4];
  const float* att2 = (const float*)d_in[5];
  const int* ei = (const int*)d_in[6];
  int E = in_sizes[6] / 2;
  float* out = (float*)d_out;

  float* ws = (float*)d_ws;
  float* h    = ws;                         // 8 MB
  float* ps   = h  + (size_t)NN * HC;       // 4 MB
  float* pd   = ps + (size_t)NN * 128;      // 4 MB
  float* raw  = pd + (size_t)NN * 128;      // 8 MB
  float* part = raw + (size_t)NN * HC;      // 64 KB
  int*   offs = (int*)(part + (size_t)NN * 2);  // NN+1 ints

  k_h_p<<<NGRP, 256, 0, stream>>>(x, W, bias, att1, ei, h, ps, pd, offs, E);
  k_agg<<<AGRID, 256, 0, stream>>>(h, ps, pd, ei, att2, offs, raw, part, E);
  k_scale<<<SCALE_BLOCKS, 256, 0, stream>>>(raw, part, out);
}